// Round 1
// baseline (1928.415 us; speedup 1.0000x reference)
//
#include <hip/hip_runtime.h>

#define E 64
#define D 50
#define SS 384
#define G4 256   // 4*E

__device__ __forceinline__ float fast_rcp(float x){ return __builtin_amdgcn_rcpf(x); }
__device__ __forceinline__ float tanh_fast(float x){
  // tanh(x) = 1 - 2/(exp(2x)+1); exp overflow->inf->+1, underflow->0->-1 (both correct)
  float e = __expf(2.0f*x);
  return 1.0f - 2.0f*fast_rcp(e + 1.0f);
}
__device__ __forceinline__ float sigmoid_fast(float x){
  return fast_rcp(1.0f + __expf(-x));
}
__device__ __forceinline__ float bcast_lane(float v, int lane){
  return __int_as_float(__builtin_amdgcn_readlane(__float_as_int(v), lane));
}

// ---------------------------------------------------------------------------
// K0: gx[b,s,j] = bias[j] + sum_k emb[sent[b,s],k] * Wih[j,k]   (both LSTMs)
// 512 blocks x 256 threads; block handles 96 rows of one LSTM's (B*S, 256).
// ---------------------------------------------------------------------------
__global__ __launch_bounds__(256) void gx_kernel(
  const int* __restrict__ sent1, const int* __restrict__ sent2,
  const float* __restrict__ emb,
  const float* __restrict__ Wih1, const float* __restrict__ bih1, const float* __restrict__ bhh1,
  const float* __restrict__ Wih2, const float* __restrict__ bih2, const float* __restrict__ bhh2,
  float* __restrict__ gx1, float* __restrict__ gx2)
{
  const int bb    = blockIdx.x;     // 0..511
  const int which = bb >> 8;
  const int chunk = bb & 255;
  const int j     = threadIdx.x;
  const int*   sent = which ? sent2 : sent1;
  const float* Wih  = which ? Wih2  : Wih1;
  const float* bA   = which ? bih2  : bih1;
  const float* bB   = which ? bhh2  : bhh1;
  float*       gx   = which ? gx2   : gx1;

  float wih[D];
  #pragma unroll
  for (int k=0;k<D;k+=2){                       // row stride 200B -> 8B aligned
    float2 v = *(const float2*)&Wih[j*D+k];
    wih[k]=v.x; wih[k+1]=v.y;
  }
  const float bias = bA[j] + bB[j];

  __shared__ __align__(16) float xb[8][52];     // 52: keeps float4 reads aligned
  const int row0 = chunk*96;
  for (int c=0;c<12;++c){
    const int r0 = row0 + c*8;
    #pragma unroll
    for (int q=0;q<2;++q){
      int tt = j + q*256;
      if (tt < 400){
        int r = tt/50;
        int k = tt - r*50;
        int idx = sent[r0 + r];
        xb[r][k] = emb[(size_t)idx*D + k];
      }
    }
    __syncthreads();
    for (int r=0;r<8;++r){
      float a0=bias, a1=0.f;
      #pragma unroll
      for (int k=0;k<48;k+=4){
        float4 xv = *(const float4*)&xb[r][k];
        a0 += xv.x*wih[k]   + xv.y*wih[k+1];
        a1 += xv.z*wih[k+2] + xv.w*wih[k+3];
      }
      a0 += xb[r][48]*wih[48];
      a1 += xb[r][49]*wih[49];
      gx[(size_t)(r0+r)*G4 + j] = a0+a1;
    }
    __syncthreads();
  }
}

// ---------------------------------------------------------------------------
// K1: both LSTM recurrences. 64 blocks (one per batch) x 256 threads.
// Thread j owns gate j; Whh row j lives in 64 VGPRs; h/c via LDS.
// Captures LSTM2 init state (s1_len) and hn (s2_len) in registers in-flight.
// ---------------------------------------------------------------------------
__global__ __launch_bounds__(256) void lstm_kernel(
  const float* __restrict__ gx1, const float* __restrict__ gx2,
  const float* __restrict__ Whh1, const float* __restrict__ Whh2,
  const int* __restrict__ s1_len, const int* __restrict__ s2_len,
  float* __restrict__ h1_all, float* __restrict__ out_all,
  float* __restrict__ hn_cap)
{
  const int b = blockIdx.x;
  const int j = threadIdx.x;
  __shared__ __align__(16) float h_lds[E];
  __shared__ float gates[G4];
  float whh[E];
  #pragma unroll
  for (int k=0;k<E;k+=4){
    float4 v = *(const float4*)&Whh1[j*E+k];
    whh[k]=v.x; whh[k+1]=v.y; whh[k+2]=v.z; whh[k+3]=v.w;
  }
  const int is_g_gate = (j>=128 && j<192);   // wave-uniform: wave2 = tanh gate
  float c_reg=0.f, gh=0.f, gc=0.f, hn=0.f;
  int idx1 = 0, idx2 = 0;
  if (j<E){ idx1 = s1_len[b*E+j]; idx2 = s2_len[b*E+j]; h_lds[j]=0.f; }
  __syncthreads();

  // ---- LSTM1 ----
  {
    const float* gx = gx1 + (size_t)b*SS*G4;
    float* hout = h1_all + (size_t)b*SS*E;
    float gx_cur = gx[j];
    float gx_n1  = gx[G4 + j];
    for (int s=0;s<SS;++s){
      int sn2 = (s+2<SS)? s+2 : SS-1;
      float gx_n2 = gx[(size_t)sn2*G4 + j];    // 2-deep prefetch (L3 latency)
      float a0=0,a1=0,a2=0,a3=0;
      #pragma unroll
      for (int k=0;k<E;k+=4){
        float4 hv = *(const float4*)&h_lds[k];
        a0 += hv.x*whh[k];   a1 += hv.y*whh[k+1];
        a2 += hv.z*whh[k+2]; a3 += hv.w*whh[k+3];
      }
      float g = ((a0+a1)+(a2+a3)) + gx_cur;
      gates[j] = is_g_gate ? tanh_fast(g) : sigmoid_fast(g);
      __syncthreads();
      if (j<E){
        float gi=gates[j], gf=gates[E+j], gg=gates[2*E+j], go=gates[3*E+j];
        c_reg = gf*c_reg + gi*gg;
        float h = go * tanh_fast(c_reg);
        h_lds[j] = h;
        hout[(size_t)s*E + j] = h;
        if (s==idx1){ gh=h; gc=c_reg; }
      }
      gx_cur = gx_n1; gx_n1 = gx_n2;
      __syncthreads();
    }
  }
  // ---- swap to LSTM2 (init = gathered state) ----
  #pragma unroll
  for (int k=0;k<E;k+=4){
    float4 v = *(const float4*)&Whh2[j*E+k];
    whh[k]=v.x; whh[k+1]=v.y; whh[k+2]=v.z; whh[k+3]=v.w;
  }
  if (j<E){ h_lds[j]=gh; c_reg=gc; }
  __syncthreads();
  {
    const float* gx = gx2 + (size_t)b*SS*G4;
    float* hout = out_all + (size_t)b*SS*E;
    float gx_cur = gx[j];
    float gx_n1  = gx[G4 + j];
    for (int s=0;s<SS;++s){
      int sn2 = (s+2<SS)? s+2 : SS-1;
      float gx_n2 = gx[(size_t)sn2*G4 + j];
      float a0=0,a1=0,a2=0,a3=0;
      #pragma unroll
      for (int k=0;k<E;k+=4){
        float4 hv = *(const float4*)&h_lds[k];
        a0 += hv.x*whh[k];   a1 += hv.y*whh[k+1];
        a2 += hv.z*whh[k+2]; a3 += hv.w*whh[k+3];
      }
      float g = ((a0+a1)+(a2+a3)) + gx_cur;
      gates[j] = is_g_gate ? tanh_fast(g) : sigmoid_fast(g);
      __syncthreads();
      if (j<E){
        float gi=gates[j], gf=gates[E+j], gg=gates[2*E+j], go=gates[3*E+j];
        c_reg = gf*c_reg + gi*gg;
        float h = go * tanh_fast(c_reg);
        h_lds[j] = h;
        hout[(size_t)s*E + j] = h;
        if (s==idx2) hn = h;
      }
      gx_cur = gx_n1; gx_n1 = gx_n2;
      __syncthreads();
    }
  }
  if (j<E) hn_cap[b*E+j] = hn;
}

// ---------------------------------------------------------------------------
// K2: base[row,f] = sum_e h1[row,e]*wy[e,f] + out[row,e]*wh[e,f]
// 1536 blocks x 256 threads; wave = one row at a time (4 rows/wave).
// wy/wh columns held in registers; h broadcast via v_readlane.
// ---------------------------------------------------------------------------
__global__ __launch_bounds__(256) void base_kernel(
  const float* __restrict__ h1_all, const float* __restrict__ out_all,
  const float* __restrict__ wy, const float* __restrict__ wh,
  float* __restrict__ base_g)
{
  const int t = threadIdx.x;
  const int wave = t>>6, lane = t&63;
  float wyc[E], whc[E];
  #pragma unroll
  for (int e=0;e<E;++e){ wyc[e]=wy[e*E+lane]; whc[e]=wh[e*E+lane]; }
  const int row0 = blockIdx.x*16 + wave*4;
  for (int r=0;r<4;++r){
    int row = row0 + r;
    float hv = h1_all[(size_t)row*E + lane];
    float ov = out_all[(size_t)row*E + lane];
    float a0=0,a1=0;
    #pragma unroll
    for (int e=0;e<E;++e){
      a0 += bcast_lane(hv,e)*wyc[e];
      a1 += bcast_lane(ov,e)*whc[e];
    }
    base_g[(size_t)row*E + lane] = a0+a1;
  }
}

// ---------------------------------------------------------------------------
// K3: attention scan, 384 sequential steps. 64 blocks x 1024 threads.
// Fused: score -> exp (no max-sub; |score| <= sum|w| ~ 51, fp32-safe)
//        -> unnormalized sum exp*h accumulated inline; normalize at end.
// Rt never materialized: rn captured in-register at s == s2_len.
// ---------------------------------------------------------------------------
__global__ __launch_bounds__(1024) void attn_kernel(
  const float* __restrict__ h1_all, const float* __restrict__ base_g,
  const float* __restrict__ w, const float* __restrict__ wr, const float* __restrict__ wt,
  const float* __restrict__ s1_s, const int* __restrict__ s2_len,
  float* __restrict__ rn_cap)
{
  const int b = blockIdx.x;
  const int t = threadIdx.x;
  const int wave = t>>6, lane = t&63;
  const int sub  = t&15;          // 16 threads per s-row
  const int e4   = sub*4;         // 4 e-columns per thread
  const int srow0 = t>>4;         // 0..63
  __shared__ __align__(16) float smemA[8192];      // wr | wt  (k*64+e layout)
  __shared__ __align__(16) float part[16*E];
  __shared__ float wave_sum[16];
  __shared__ __align__(16) float r_lds[E];
  __shared__ __align__(16) float rw_lds[E];
  __shared__ __align__(16) float rt_lds[E];
  const float* h1b = h1_all + (size_t)b*SS*E;
  const float* bsb = base_g + (size_t)b*SS*E;

  for (int i=t;i<8192;i+=1024) smemA[i] = (i<4096)? wr[i] : wt[i-4096];
  int idx2 = 0; float rn_keep = 0.f;
  if (t<E){ r_lds[t]=0.f; rw_lds[t]=0.f; idx2 = s2_len[b*E+t]; }
  const float4 wv4 = *(const float4*)&w[e4];
  __syncthreads();

  float psum_r=0.f, tot_r=0.f;
  for (int s=0;s<SS;++s){
    float4 rwv = *(const float4*)&rw_lds[e4];
    float ax=0,ay=0,az=0,aw=0, sum_acc=0;
    #pragma unroll
    for (int p=0;p<6;++p){
      int srow = srow0 + p*64;
      float4 bse = *(const float4*)&bsb[(size_t)srow*E + e4];
      float4 hv  = *(const float4*)&h1b[(size_t)srow*E + e4];
      float m0 = tanh_fast(bse.x + rwv.x);
      float m1 = tanh_fast(bse.y + rwv.y);
      float m2 = tanh_fast(bse.z + rwv.z);
      float m3 = tanh_fast(bse.w + rwv.w);
      float sc = m0*wv4.x + m1*wv4.y + m2*wv4.z + m3*wv4.w;
      sc += __shfl_xor(sc,1); sc += __shfl_xor(sc,2);   // butterfly: all 16 get score
      sc += __shfl_xor(sc,4); sc += __shfl_xor(sc,8);
      float s1v = s1_s[b*SS + srow];
      float masked = s1v*sc - (1.0f - s1v)*1e12f;
      float ex = __expf(masked);
      sum_acc += ex;                                    // identical across the 16 lanes
      ax += ex*hv.x; ay += ex*hv.y; az += ex*hv.z; aw += ex*hv.w;
    }
    // reduce the 4 row-subgroups of the wave (lanes l, l^16, l^32, l^48)
    ax += __shfl_xor(ax,16); ax += __shfl_xor(ax,32);
    ay += __shfl_xor(ay,16); ay += __shfl_xor(ay,32);
    az += __shfl_xor(az,16); az += __shfl_xor(az,32);
    aw += __shfl_xor(aw,16); aw += __shfl_xor(aw,32);
    sum_acc += __shfl_xor(sum_acc,16); sum_acc += __shfl_xor(sum_acc,32);
    if (lane < 16){ float4 v = make_float4(ax,ay,az,aw); *(float4*)&part[wave*E + lane*4] = v; }
    if (lane == 0) wave_sum[wave] = sum_acc;
    __syncthreads();
    if (wave==0){                       // reduce partials (per-e and total)
      float ps=0;
      #pragma unroll
      for (int wvv=0;wvv<16;++wvv) ps += part[wvv*E+lane];
      float tt2=0;
      #pragma unroll
      for (int wvv=0;wvv<16;++wvv) tt2 += wave_sum[wvv];
      psum_r=ps; tot_r=tt2;
    } else if (wave==1){                // rt = tanh(r_old @ wt), concurrent with wave0
      float b0=0,b1=0;
      #pragma unroll
      for (int k=0;k<E;k+=2){
        b0 += r_lds[k]   * smemA[4096 + k*E + lane];
        b1 += r_lds[k+1] * smemA[4096 + (k+1)*E + lane];
      }
      rt_lds[lane] = tanh_fast(b0+b1);
    }
    __syncthreads();
    if (wave==0){
      float rnew = psum_r * fast_rcp(tot_r) + rt_lds[lane];
      r_lds[lane] = rnew;
      if (s==idx2) rn_keep = rnew;
      float c0=0,c1=0;                  // rw = r_new @ wr for next step
      #pragma unroll
      for (int k=0;k<E;k+=2){
        c0 += bcast_lane(rnew,k)   * smemA[k*E + lane];
        c1 += bcast_lane(rnew,k+1) * smemA[(k+1)*E + lane];
      }
      rw_lds[lane] = c0+c1;
    }
    __syncthreads();
  }
  if (t<E) rn_cap[b*E+t] = rn_keep;
}

// ---------------------------------------------------------------------------
// K4: final MLP. 64 blocks x 128 threads.
// ---------------------------------------------------------------------------
__global__ __launch_bounds__(128) void final_kernel(
  const float* __restrict__ rn_cap, const float* __restrict__ hn_cap,
  const float* __restrict__ wp, const float* __restrict__ wx,
  const float* __restrict__ l1W, const float* __restrict__ l1b,
  const float* __restrict__ lW, const float* __restrict__ lb,
  float* __restrict__ out)
{
  const int b = blockIdx.x, t = threadIdx.x;
  __shared__ float rn[E], hn[E], hid1[E], hid2[128];
  if (t<E){ rn[t]=rn_cap[b*E+t]; hn[t]=hn_cap[b*E+t]; }
  __syncthreads();
  if (t<E){
    float a0=0,a1=0;
    #pragma unroll
    for (int k=0;k<E;++k){
      a0 += rn[k]*wp[k*E+t];
      a1 += hn[k]*wx[k*E+t];
    }
    hid1[t] = tanh_fast(a0+a1);
  }
  __syncthreads();
  {
    float acc = l1b[t];
    #pragma unroll
    for (int k=0;k<E;++k) acc += hid1[k]*l1W[t*E+k];
    hid2[t] = tanh_fast(acc);
  }
  __syncthreads();
  if (t<4){
    float acc = lb[t];
    #pragma unroll
    for (int k=0;k<128;++k) acc += hid2[k]*lW[t*128+k];
    out[b*4+t] = acc;
  }
}

extern "C" void kernel_launch(void* const* d_in, const int* in_sizes, int n_in,
                              void* d_out, int out_size, void* d_ws, size_t ws_size,
                              hipStream_t stream)
{
  const int*   sent1 = (const int*)  d_in[0];
  const int*   sent2 = (const int*)  d_in[1];
  const int*   s1len = (const int*)  d_in[2];
  const int*   s2len = (const int*)  d_in[3];
  const float* s1s   = (const float*)d_in[4];
  // d_in[5] = s2_s (unused by reference math)
  const float* emb   = (const float*)d_in[6];
  const float* Wih1  = (const float*)d_in[7];
  const float* Whh1  = (const float*)d_in[8];
  const float* bih1  = (const float*)d_in[9];
  const float* bhh1  = (const float*)d_in[10];
  const float* Wih2  = (const float*)d_in[11];
  const float* Whh2  = (const float*)d_in[12];
  const float* bih2  = (const float*)d_in[13];
  const float* bhh2  = (const float*)d_in[14];
  const float* wy    = (const float*)d_in[15];
  const float* wh    = (const float*)d_in[16];
  const float* w     = (const float*)d_in[17];
  const float* wp    = (const float*)d_in[18];
  const float* wx    = (const float*)d_in[19];
  const float* wr    = (const float*)d_in[20];
  const float* wt    = (const float*)d_in[21];
  const float* l1W   = (const float*)d_in[22];
  const float* l1b   = (const float*)d_in[23];
  const float* lW    = (const float*)d_in[24];
  const float* lb    = (const float*)d_in[25];
  float* out = (float*)d_out;

  float* ws  = (float*)d_ws;
  float* gx1 = ws;                         // 64*384*256 = 6291456 floats
  float* gx2 = gx1 + 6291456;
  float* h1  = gx2 + 6291456;              // 64*384*64 = 1572864
  float* outa= h1  + 1572864;
  float* base= outa + 1572864;
  float* rnc = base + 1572864;             // 4096
  float* hnc = rnc + 4096;

  hipLaunchKernelGGL(gx_kernel, dim3(512), dim3(256), 0, stream,
    sent1, sent2, emb, Wih1, bih1, bhh1, Wih2, bih2, bhh2, gx1, gx2);
  hipLaunchKernelGGL(lstm_kernel, dim3(64), dim3(256), 0, stream,
    gx1, gx2, Whh1, Whh2, s1len, s2len, h1, outa, hnc);
  hipLaunchKernelGGL(base_kernel, dim3(1536), dim3(256), 0, stream,
    h1, outa, wy, wh, base);
  hipLaunchKernelGGL(attn_kernel, dim3(64), dim3(1024), 0, stream,
    h1, base, w, wr, wt, s1s, s2len, rnc);
  hipLaunchKernelGGL(final_kernel, dim3(64), dim3(128), 0, stream,
    rnc, hnc, wp, wx, l1W, l1b, lW, lb, out);
}